// Round 5
// baseline (7959.260 us; speedup 1.0000x reference)
//
#include <hip/hip_runtime.h>

// ---------------- problem constants ----------------
#define NN      16384      // total nodes
#define TSTEPS  32
#define SG      256        // graphs
#define NE      262144
#define NPANEL  24         // 22 panels for xl@Wih (21x384 + 128) + 2 for lh@Whh (384+128)
#define GSTRIDE 524288u    // 256*2048 floats per panel partial

// ---------------- workspace layout (float offsets) ----------------
#define OFF_ENC_MEM   0u
#define OFF_ENC_SPK   2097152u
#define OFF_C1_MEM    4194304u
#define OFF_C1_SPK    6291456u     // == xl [256][8192]
#define OFF_LH        8388608u
#define OFF_LC        8519680u
#define OFF_H1_MEM    8650752u
#define OFF_H1_SPK    8716288u
#define OFF_H2_MEM    8781824u
#define OFF_H2_SPK    8782848u
#define OFF_H2_SUM    8783872u
#define ZERO_FLOATS   8784896u     // everything below here zeroed each launch
#define OFF_BASES     8784896u
#define OFF_COMB      9833472u
#define OFF_GATES     10357760u    // 256 x 2048
#define OFF_PART      10882048u    // 24 x 256 x 2048 panel partials
#define OFF_DINV      23464960u
#define OFF_COLW      23481344u
#define FLOAT_END     23743488u
// int region (offsets from ibase)
#define IOFF_DEG      0
#define IOFF_FILL     16384
#define IOFF_ROWPTR   32768
#define IOFF_EID      49153
#define IOFF_COL      311297
#define INT_COUNT     573441

// ---------------- graph preprocessing ----------------
__global__ void k_deg(const int* __restrict__ ei, int* __restrict__ deg) {
  int e = blockIdx.x * 256 + threadIdx.x;
  if (e < NE) atomicAdd(&deg[ei[NE + e]], 1);
}

__global__ void k_dinv(const int* __restrict__ deg, float* __restrict__ dinv) {
  int n = blockIdx.x * 256 + threadIdx.x;
  if (n < NN) dinv[n] = __fdiv_rn(1.0f, __fsqrt_rn((float)(deg[n] + 1)));  // +1 self-loop
}

__global__ void k_scan(const int* __restrict__ deg, int* __restrict__ rowp) {
  __shared__ int sdata[1024];
  int tid = threadIdx.x;
  int base = tid * 16;
  int loc[16];
  int sum = 0;
  #pragma unroll
  for (int i = 0; i < 16; ++i) { loc[i] = sum; sum += deg[base + i]; }
  sdata[tid] = sum;
  __syncthreads();
  for (int off = 1; off < 1024; off <<= 1) {
    int v = 0;
    if (tid >= off) v = sdata[tid - off];
    __syncthreads();
    sdata[tid] += v;
    __syncthreads();
  }
  int excl = (tid == 0) ? 0 : sdata[tid - 1];
  #pragma unroll
  for (int i = 0; i < 16; ++i) rowp[base + i] = excl + loc[i];
  if (tid == 1023) rowp[NN] = sdata[1023];
}

__global__ void k_scatter(const int* __restrict__ ei, const int* __restrict__ rowp,
                          int* __restrict__ fill, int* __restrict__ eid) {
  int e = blockIdx.x * 256 + threadIdx.x;
  if (e >= NE) return;
  int d = ei[NE + e];
  int pos = rowp[d] + atomicAdd(&fill[d], 1);
  eid[pos] = e;
}

// sort each adjacency list by EDGE ID (unique keys) -> summation order == scatter-add order
__global__ void k_sortadj(const int* __restrict__ rowp, int* __restrict__ eid,
                          const int* __restrict__ ei, const float* __restrict__ dinv,
                          int* __restrict__ col, float* __restrict__ colw) {
  int d = blockIdx.x * 256 + threadIdx.x;
  if (d >= NN) return;
  int r0 = rowp[d], r1 = rowp[d + 1];
  for (int i = r0 + 1; i < r1; ++i) {
    int key = eid[i];
    int j = i - 1;
    while (j >= r0 && eid[j] > key) { eid[j + 1] = eid[j]; --j; }
    eid[j + 1] = key;
  }
  for (int i = r0; i < r1; ++i) {
    int s = ei[eid[i]];
    col[i] = s;
    colw[i] = dinv[s];
  }
}

// ---------------- per-timestep kernels ----------------
// fused enc LIF + bases/comb matmuls (64 nodes/block).
// enc LIF chain and per-output fma chains identical to round-4 (bit-exact).
__global__ __launch_bounds__(256) void k_encbases(
    const float* __restrict__ x, const float* __restrict__ encW, const float* __restrict__ encB,
    float* __restrict__ enc_mem, float* __restrict__ enc_spk,
    const float* __restrict__ basesW, const float* __restrict__ basesB,
    const float* __restrict__ combW, const float* __restrict__ combB,
    float* __restrict__ bases, float* __restrict__ comb, int t) {
  __shared__ float xs[64][8];
  __shared__ float sp[64 * 129];   // [node][j]
  __shared__ float ob[64 * 65];    // bases out [node][ch]
  __shared__ float oc[64 * 33];    // comb out [node][ch]
  const int tid = threadIdx.x;
  const int nb = blockIdx.x * 64;
  #pragma unroll
  for (int r = 0; r < 2; ++r) {
    int idx = r * 256 + tid;       // 0..511
    int n = idx >> 3, c = idx & 7;
    xs[n][c] = x[(size_t)(nb + n) * 256 + (size_t)c * 32 + t];
  }
  __syncthreads();
  // enc LIF for 64 nodes x 128 ch (j lane-consecutive; xs row broadcast per wave)
  #pragma unroll 4
  for (int k = 0; k < 32; ++k) {
    int idx = k * 256 + tid;
    int n = idx >> 7, j = idx & 127;
    float dot = 0.f;
    #pragma unroll
    for (int c = 0; c < 8; ++c) dot = __fmaf_rn(xs[n][c], encW[c * 128 + j], dot);
    size_t gi = (size_t)nb * 128 + idx;
    float m = enc_mem[gi], s = enc_spk[gi];
    float nm = __fadd_rn(__fadd_rn(__fmul_rn(__fmul_rn(m, 0.2f), __fsub_rn(1.f, s)), dot), encB[j]);
    enc_mem[gi] = nm;
    float spike = nm > 0.5f ? 1.f : 0.f;
    enc_spk[gi] = spike;
    sp[n * 129 + j] = spike;
  }
  __syncthreads();
  // lane = node, 32/16 independent channel chains per lane; weights via scalar loads
  const int lane = tid & 63;
  const int w = tid >> 6;
  const float* spn = sp + lane * 129;
  if (w < 2) {
    const int ch0 = w * 32;
    const float* Wp = basesW + ch0;
    float acc[32];
    #pragma unroll
    for (int c = 0; c < 32; ++c) acc[c] = 0.f;
    for (int j = 0; j < 128; ++j) {
      const float s = spn[j];
      const float* wr = Wp + j * 64;
      #pragma unroll
      for (int c = 0; c < 32; ++c) acc[c] = __fmaf_rn(s, wr[c], acc[c]);
    }
    #pragma unroll
    for (int c = 0; c < 32; ++c) ob[lane * 65 + ch0 + c] = acc[c];
  } else {
    const int ch0 = (w - 2) * 16;
    const float* Wp = combW + ch0;
    float acc[16];
    #pragma unroll
    for (int c = 0; c < 16; ++c) acc[c] = 0.f;
    for (int j = 0; j < 128; ++j) {
      const float s = spn[j];
      const float* wr = Wp + j * 32;
      #pragma unroll
      for (int c = 0; c < 16; ++c) acc[c] = __fmaf_rn(s, wr[c], acc[c]);
    }
    #pragma unroll
    for (int c = 0; c < 16; ++c) oc[lane * 33 + ch0 + c] = acc[c];
  }
  __syncthreads();
  #pragma unroll
  for (int r = 0; r < 16; ++r) {
    int idx = r * 256 + tid;
    int n = idx >> 6, ch = idx & 63;
    bases[(size_t)(nb + n) * 64 + ch] = __fadd_rn(ob[n * 65 + ch], basesB[ch]);
  }
  #pragma unroll
  for (int r = 0; r < 8; ++r) {
    int idx = r * 256 + tid;
    int n = idx >> 5, ch = idx & 31;
    comb[(size_t)(nb + n) * 32 + ch] = __fadd_rn(oc[n * 33 + ch], combB[ch]);
  }
}

// fused: symnorm aggregation (edge-order scatter-add) -> einsum -> conv LIF -> c1 spike
__global__ __launch_bounds__(256) void k_aggconv(
    const float* __restrict__ bases, const float* __restrict__ comb,
    const float* __restrict__ dinv, const int* __restrict__ rowp,
    const int* __restrict__ col, const float* __restrict__ colw,
    const float* __restrict__ convB,
    float* __restrict__ c1_mem, float* __restrict__ c1_spk) {
  __shared__ float aggl[4][64];
  __shared__ float combl[4][32];
  int w = threadIdx.x >> 6;
  int m = threadIdx.x & 63;
  int d = blockIdx.x * 4 + w;
  float dd = dinv[d];
  int r0 = rowp[d], r1 = rowp[d + 1];
  float acc = 0.f;
  for (int r = r0; r < r1; ++r) {
    int s = col[r];
    float ew  = __fmul_rn(colw[r], dd);
    float upd = __fmul_rn(ew, bases[(size_t)s * 64 + m]);
    acc = __fadd_rn(acc, upd);
  }
  {
    float ew  = __fmul_rn(dd, dd);
    float upd = __fmul_rn(ew, bases[(size_t)d * 64 + m]);
    acc = __fadd_rn(acc, upd);
  }
  aggl[w][m] = acc;
  if (m < 32) combl[w][m] = comb[(size_t)d * 32 + m];
  __syncthreads();
  #pragma unroll
  for (int half = 0; half < 2; ++half) {
    int j = m + half * 64;
    int h = j >> 4, f = j & 15;
    float cv = 0.f;
    #pragma unroll
    for (int b = 0; b < 4; ++b)
      cv = __fadd_rn(cv, __fmul_rn(combl[w][h * 4 + b], aggl[w][b * 16 + f]));
    cv = __fadd_rn(cv, convB[j]);
    int idx = d * 128 + j;
    float cm = c1_mem[idx], cs = c1_spk[idx];
    float nm = __fadd_rn(__fmul_rn(__fmul_rn(cm, 0.2f), __fsub_rn(1.f, cs)), cv);
    c1_mem[idx] = nm;
    c1_spk[idx] = nm > 0.5f ? 1.f : 0.f;
  }
}

// one BLAS panel of the gates GEMM: part[z] = A[:, panel_z] @ B[panel_z, :]
// BK=8; A transposed in LDS (only 4.2KB); B streamed straight into registers
// (per-wave B row-read = two contiguous 256B spans -> fully coalesced, L1/L2-hit).
// This moves the k-loop bottleneck off the single per-CU LDS unit onto the 4 SIMDs.
// acc chain stays ascending-k fma-from-0 per (m,u) -> bit-exact.
__global__ __launch_bounds__(256, 3) void k_gpanel(
    const float* __restrict__ xl, const float* __restrict__ lh,
    const float* __restrict__ Wih, const float* __restrict__ Whh,
    float* __restrict__ part) {
  __shared__ __align__(16) float Ast[8][132];   // [k][m] transposed
  const int tid = threadIdx.x;
  const int tx = tid & 15, ty = tid >> 4;
  const int n0 = blockIdx.x * 128;
  const int m0 = blockIdx.y * 128;
  const int z  = blockIdx.z;

  const float* Asrc; const float* Bsrc; int lda, k0, klen;
  if (z < 22) { Asrc = xl; Bsrc = Wih; lda = 8192; k0 = z * 384; klen = (z == 21) ? 128 : 384; }
  else        { Asrc = lh; Bsrc = Whh; lda = 512;  k0 = (z == 22) ? 0 : 384; klen = (z == 22) ? 384 : 128; }

  float acc[8][8];
  #pragma unroll
  for (int i = 0; i < 8; ++i)
    #pragma unroll
    for (int j = 0; j < 8; ++j) acc[i][j] = 0.f;

  const int arow = tid >> 1;            // 0..127
  const int acol = (tid & 1) * 4;       // 0 or 4

  const int nkt = klen >> 3;
  for (int kt = 0; kt < nkt; ++kt) {
    const int kb = k0 + (kt << 3);
    // B -> registers (issued before the barrier = prefetch window)
    float4 b0r[8], b1r[8];
    const float* bp = Bsrc + (size_t)kb * 2048 + n0 + tx * 4;
    #pragma unroll
    for (int kk = 0; kk < 8; ++kk) {
      b0r[kk] = *(const float4*)(bp + kk * 2048);
      b1r[kk] = *(const float4*)(bp + kk * 2048 + 64);
    }
    __syncthreads();
    {   // A tile -> transposed LDS (1 float4 per thread)
      const float4 v = *(const float4*)(Asrc + (size_t)(m0 + arow) * lda + kb + acol);
      Ast[acol + 0][arow] = v.x; Ast[acol + 1][arow] = v.y;
      Ast[acol + 2][arow] = v.z; Ast[acol + 3][arow] = v.w;
    }
    __syncthreads();
    #pragma unroll
    for (int kk = 0; kk < 8; ++kk) {
      const float4 a0 = *(const float4*)&Ast[kk][ty * 4];
      const float4 a1 = *(const float4*)&Ast[kk][64 + ty * 4];
      const float av[8] = {a0.x, a0.y, a0.z, a0.w, a1.x, a1.y, a1.z, a1.w};
      const float bv[8] = {b0r[kk].x, b0r[kk].y, b0r[kk].z, b0r[kk].w,
                           b1r[kk].x, b1r[kk].y, b1r[kk].z, b1r[kk].w};
      #pragma unroll
      for (int i = 0; i < 8; ++i)
        #pragma unroll
        for (int j = 0; j < 8; ++j)
          acc[i][j] = __fmaf_rn(av[i], bv[j], acc[i][j]);
    }
  }
  float* dstz = part + (size_t)z * GSTRIDE + (size_t)m0 * 2048 + n0;
  #pragma unroll
  for (int i = 0; i < 8; ++i) {
    const int mr = ((i >> 2) << 6) + ty * 4 + (i & 3);
    float* row = dstz + (size_t)mr * 2048;
    *(float4*)(row + tx * 4)      = make_float4(acc[i][0], acc[i][1], acc[i][2], acc[i][3]);
    *(float4*)(row + 64 + tx * 4) = make_float4(acc[i][4], acc[i][5], acc[i][6], acc[i][7]);
  }
}

// combine panel partials strictly left-to-right (matches round-2 "tih += accP" chain)
__global__ __launch_bounds__(256) void k_combine(
    const float* __restrict__ part, const float* __restrict__ bih,
    const float* __restrict__ bhh, float* __restrict__ gates) {
  const int idx = blockIdx.x * 256 + threadIdx.x;    // m*2048 + u
  const float* p = part + idx;
  float tih = p[0];
  #pragma unroll
  for (int zz = 1; zz < 22; ++zz) tih = __fadd_rn(tih, p[(size_t)zz * GSTRIDE]);
  const float thh = __fadd_rn(p[22u * GSTRIDE], p[23u * GSTRIDE]);
  const int u = idx & 2047;
  gates[idx] = __fadd_rn(__fadd_rn(__fadd_rn(tih, bih[u]), thh), bhh[u]);
}

// fused: gate spikes -> LSTM cell -> fc1 LIF (384+128 panels) -> fc2 LIF -> h2 accum
__global__ __launch_bounds__(256) void k_cell(
    const float* __restrict__ gates,
    float* __restrict__ lc, float* __restrict__ lh,
    const float* __restrict__ fc1W, const float* __restrict__ fc1b,
    const float* __restrict__ fc2W, const float* __restrict__ fc2b,
    float* __restrict__ h1_mem, float* __restrict__ h1_spk,
    float* __restrict__ h2_mem, float* __restrict__ h2_spk, float* __restrict__ h2_sum) {
  __shared__ float lhl[512];
  __shared__ float sp1l[256];
  const int s = blockIdx.x;
  const int p = threadIdx.x;
  #pragma unroll
  for (int half = 0; half < 2; ++half) {
    const int h = p + half * 256;
    const float giv = gates[(size_t)s * 2048 + h];
    const float gfv = gates[(size_t)s * 2048 + 512 + h];
    const float ggv = gates[(size_t)s * 2048 + 1024 + h];
    const float gov = gates[(size_t)s * 2048 + 1536 + h];
    const float iv = giv > 0.f ? 1.f : 0.f;
    const float fv = gfv > 0.f ? 1.f : 0.f;
    const float gv = ggv > 0.f ? 1.f : 0.f;
    const float ov = gov > 0.f ? 1.f : 0.f;
    const int li = s * 512 + h;
    const float lcv = __fadd_rn(__fmul_rn(fv, lc[li]), __fmul_rn(iv, gv));
    lc[li] = lcv;
    const float lhv = __fmul_rn(lcv, ov);
    lh[li] = lhv;
    lhl[h] = lhv;
  }
  __syncthreads();
  float a0 = 0.f, a1 = 0.f;
  #pragma unroll 8
  for (int q = 0; q < 384; ++q) a0 = __fmaf_rn(lhl[q], fc1W[q * 256 + p], a0);
  #pragma unroll 8
  for (int q = 384; q < 512; ++q) a1 = __fmaf_rn(lhl[q], fc1W[q * 256 + p], a1);
  const float dot1 = __fadd_rn(a0, a1);
  const int i1 = s * 256 + p;
  const float m1 = h1_mem[i1], s1o = h1_spk[i1];
  const float nm1 = __fadd_rn(__fadd_rn(__fmul_rn(__fmul_rn(m1, 0.2f), __fsub_rn(1.f, s1o)), dot1), fc1b[p]);
  h1_mem[i1] = nm1;
  const float sp1 = nm1 > 0.5f ? 1.f : 0.f;
  h1_spk[i1] = sp1;
  sp1l[p] = sp1;
  __syncthreads();
  if (p < 4) {
    float acc = 0.f;
    for (int q = 0; q < 256; ++q) acc = __fmaf_rn(sp1l[q], fc2W[q * 4 + p], acc);
    const int i2 = s * 4 + p;
    const float m2 = h2_mem[i2], s2o = h2_spk[i2];
    const float nm2 = __fadd_rn(__fadd_rn(__fmul_rn(__fmul_rn(m2, 0.2f), __fsub_rn(1.f, s2o)), acc), fc2b[p]);
    h2_mem[i2] = nm2;
    const float sp2 = nm2 > 0.5f ? 1.f : 0.f;
    h2_spk[i2] = sp2;
    h2_sum[i2] = __fadd_rn(h2_sum[i2], sp2);
  }
}

__global__ void k_out(const float* __restrict__ h2_sum, float* __restrict__ out) {
  int i = blockIdx.x * 256 + threadIdx.x;
  if (i < SG * 4) out[i] = __fmul_rn(h2_sum[i], 0.03125f);
}

// ---------------- launch ----------------
extern "C" void kernel_launch(void* const* d_in, const int* in_sizes, int n_in,
                              void* d_out, int out_size, void* d_ws, size_t ws_size,
                              hipStream_t stream) {
  const float* x      = (const float*)d_in[0];
  const int*   ei     = (const int*)  d_in[1];
  const float* encW   = (const float*)d_in[2];
  const float* encB   = (const float*)d_in[3];
  const float* basesW = (const float*)d_in[4];
  const float* basesB = (const float*)d_in[5];
  const float* combW  = (const float*)d_in[6];
  const float* combB  = (const float*)d_in[7];
  const float* convB  = (const float*)d_in[8];
  const float* Wih    = (const float*)d_in[9];
  const float* Whh    = (const float*)d_in[10];
  const float* bih    = (const float*)d_in[11];
  const float* bhh    = (const float*)d_in[12];
  const float* fc1W   = (const float*)d_in[13];
  const float* fc1b   = (const float*)d_in[14];
  const float* fc2W   = (const float*)d_in[15];
  const float* fc2b   = (const float*)d_in[16];

  float* ws = (float*)d_ws;
  float* enc_mem = ws + OFF_ENC_MEM;
  float* enc_spk = ws + OFF_ENC_SPK;
  float* c1_mem  = ws + OFF_C1_MEM;
  float* c1_spk  = ws + OFF_C1_SPK;   // xl
  float* lhp     = ws + OFF_LH;
  float* lcp     = ws + OFF_LC;
  float* h1_mem  = ws + OFF_H1_MEM;
  float* h1_spk  = ws + OFF_H1_SPK;
  float* h2_mem  = ws + OFF_H2_MEM;
  float* h2_spk  = ws + OFF_H2_SPK;
  float* h2_sum  = ws + OFF_H2_SUM;
  float* bases   = ws + OFF_BASES;
  float* comb    = ws + OFF_COMB;
  float* gates   = ws + OFF_GATES;
  float* partp   = ws + OFF_PART;
  float* dinv    = ws + OFF_DINV;
  float* colw    = ws + OFF_COLW;
  int* ibase = (int*)((char*)d_ws + (size_t)FLOAT_END * 4);
  int* deg  = ibase + IOFF_DEG;
  int* fill = ibase + IOFF_FILL;
  int* rowp = ibase + IOFF_ROWPTR;
  int* eid  = ibase + IOFF_EID;
  int* col  = ibase + IOFF_COL;

  hipMemsetAsync(ws, 0, (size_t)ZERO_FLOATS * 4, stream);
  hipMemsetAsync(ibase, 0, 32768 * 4, stream);

  k_deg    <<<NE / 256, 256, 0, stream>>>(ei, deg);
  k_dinv   <<<NN / 256, 256, 0, stream>>>(deg, dinv);
  k_scan   <<<1, 1024, 0, stream>>>(deg, rowp);
  k_scatter<<<NE / 256, 256, 0, stream>>>(ei, rowp, fill, eid);
  k_sortadj<<<NN / 256, 256, 0, stream>>>(rowp, eid, ei, dinv, col, colw);

  for (int t = 0; t < TSTEPS; ++t) {
    k_encbases<<<NN / 64, 256, 0, stream>>>(x, encW, encB, enc_mem, enc_spk,
                                            basesW, basesB, combW, combB, bases, comb, t);
    k_aggconv <<<NN / 4, 256, 0, stream>>>(bases, comb, dinv, rowp, col, colw, convB, c1_mem, c1_spk);
    k_gpanel  <<<dim3(16, 2, NPANEL), 256, 0, stream>>>(c1_spk, lhp, Wih, Whh, partp);
    k_combine <<<2048, 256, 0, stream>>>(partp, bih, bhh, gates);
    k_cell    <<<SG, 256, 0, stream>>>(gates, lcp, lhp, fc1W, fc1b, fc2W, fc2b,
                                       h1_mem, h1_spk, h2_mem, h2_spk, h2_sum);
  }
  k_out<<<4, 256, 0, stream>>>(h2_sum, (float*)d_out);
}